// Round 3
// baseline (1151.313 us; speedup 1.0000x reference)
//
#include <hip/hip_runtime.h>
#include <hip/hip_bf16.h>

#define BT_ROWS 32768   // B*T
#define CDIM    256
#define VDIM    2048
#define TDIM    2048

// ---------------------------------------------------------------------------
// K1: fused f32 GEMM (logits = z @ e^T) + online logsumexp + argmax per row.
// grid 512 x 256 thr (1 block/CU: 128KB LDS). Block: 64 rows x V=2048, K=256.
// LDS: zs[64][256] (64KB) + es double-buffered 2 x [256 v][32 k] (2x32KB).
// Thread tile 8 rows x 8 cols. es granule swizzle: float4 granule gk of row c
// stored at gk ^ ((c>>3)&7); reader's row c = tx*8+j has (c>>3)&7 == tx&7, so
// read index (g ^ (tx&7)) recovers granule g. zv reads are half-wave broadcast
// (free); ev reads run at the b128 BW floor -> VALU-bound by design.
// Double buffering: chunk c+1 staged (global->reg->LDS) while chunk c computes;
// ONE barrier per chunk keeps the single-wave-per-SIMD pipeline from stalling
// on global latency.
// ---------------------------------------------------------------------------
__global__ __launch_bounds__(256, 1)
void k1_gemm_lse(const float* __restrict__ z, const float* __restrict__ e,
                 float* __restrict__ lp, float* __restrict__ ls_arr,
                 int* __restrict__ amax_arr)
{
    __shared__ float zs[64 * 256];
    __shared__ float es[2][256 * 32];
    const int tid  = threadIdx.x;
    const int row0 = blockIdx.x * 64;
    const int tx   = tid & 31;      // col group: 32 groups x 8 cols = 256
    const int ty   = tid >> 5;      // row group: 8 groups x 8 rows = 64
    const int xsw  = tx & 7;

    // stage z block: 64x256 f32 = 4096 float4, coalesced, conflict-free
    {
        const float4* zg = (const float4*)(z + (size_t)row0 * CDIM);
        float4* zl = (float4*)zs;
        #pragma unroll
        for (int p = 0; p < 16; ++p) zl[p * 256 + tid] = zg[p * 256 + tid];
    }

    const float4* eg = (const float4*)e;

    // stage one es chunk: chunk index c -> vt = c>>3 (v block), kh = c&7 (k block)
    // 256 v-rows x 8 granules (32 k floats) = 2048 float4; 8 per thread.
    #define STAGE_ES(buf, chunk)                                               \
        {                                                                      \
            const int vt_ = (chunk) >> 3, kh_ = (chunk) & 7;                   \
            float4* el = (float4*)es[buf];                                     \
            _Pragma("unroll")                                                  \
            for (int p = 0; p < 8; ++p) {                                      \
                int gi = p * 256 + tid;                                        \
                int c  = gi >> 3;                                              \
                int gk = gi & 7;                                               \
                int sw = (c >> 3) & 7;                                         \
                el[c * 8 + (gk ^ sw)] = eg[(vt_ * 256 + c) * 64 + kh_ * 8 + gk]; \
            }                                                                  \
        }

    STAGE_ES(0, 0)
    __syncthreads();

    float m[8], s[8]; int am[8];
    #pragma unroll
    for (int i = 0; i < 8; ++i) { m[i] = -3.0e38f; s[i] = 0.f; am[i] = 0; }

    for (int vt = 0; vt < 8; ++vt) {
        const int v0 = vt * 256;
        float acc[8][8];
        #pragma unroll
        for (int i = 0; i < 8; ++i)
            #pragma unroll
            for (int j = 0; j < 8; ++j) acc[i][j] = 0.f;

        for (int kh = 0; kh < 8; ++kh) {
            const int chunk = vt * 8 + kh;
            const int cur = chunk & 1;
            if (chunk + 1 < 64) STAGE_ES(cur ^ 1, chunk + 1)

            #pragma unroll
            for (int k4 = 0; k4 < 32; k4 += 4) {
                float4 zv[8], ev[8];
                #pragma unroll
                for (int i = 0; i < 8; ++i)
                    zv[i] = *(const float4*)&zs[(ty * 8 + i) * 256 + kh * 32 + k4];
                const int g = k4 >> 2;
                #pragma unroll
                for (int j = 0; j < 8; ++j)
                    ev[j] = *(const float4*)&es[cur][(tx * 8 + j) * 32 + ((g ^ xsw) & 7) * 4];
                #pragma unroll
                for (int i = 0; i < 8; ++i)
                    #pragma unroll
                    for (int j = 0; j < 8; ++j) {
                        acc[i][j] += zv[i].x * ev[j].x;
                        acc[i][j] += zv[i].y * ev[j].y;
                        acc[i][j] += zv[i].z * ev[j].z;
                        acc[i][j] += zv[i].w * ev[j].w;
                    }
            }
            __syncthreads();   // next iter overwrites es[cur]; also fences stage of es[cur^1]
        }

        // per-row online stats (max/argmax/sumexp) + raw logit stores
        #pragma unroll
        for (int i = 0; i < 8; ++i) {
            float tv = acc[i][0]; int tix = v0 + tx * 8;
            #pragma unroll
            for (int j = 1; j < 8; ++j)
                if (acc[i][j] > tv) { tv = acc[i][j]; tix = v0 + tx * 8 + j; }
            #pragma unroll
            for (int off = 1; off < 32; off <<= 1) {   // stays within 32-lane half
                float ov = __shfl_xor(tv, off);
                int   oi = __shfl_xor(tix, off);
                if (ov > tv || (ov == tv && oi < tix)) { tv = ov; tix = oi; }
            }
            float mnew = fmaxf(m[i], tv);
            if (tv > m[i]) am[i] = tix;   // strict > keeps earliest index on ties
            float ps = 0.f;
            #pragma unroll
            for (int j = 0; j < 8; ++j) ps += expf(acc[i][j] - mnew);
            #pragma unroll
            for (int off = 1; off < 32; off <<= 1) ps += __shfl_xor(ps, off);
            s[i] = s[i] * expf(m[i] - mnew) + ps;
            m[i] = mnew;

            float* lpr = lp + (size_t)(row0 + ty * 8 + i) * VDIM + v0 + tx * 8;
            *(float4*)lpr       = make_float4(acc[i][0], acc[i][1], acc[i][2], acc[i][3]);
            *(float4*)(lpr + 4) = make_float4(acc[i][4], acc[i][5], acc[i][6], acc[i][7]);
        }
    }

    if (tx == 0) {
        #pragma unroll
        for (int i = 0; i < 8; ++i) {
            int r = row0 + ty * 8 + i;
            ls_arr[r]   = m[i] + logf(s[i]);
            amax_arr[r] = am[i];
        }
    }
    #undef STAGE_ES
}

// ---------------------------------------------------------------------------
// K2: in-place normalize raw logits -> log_probs (lp[row][v] -= ls[row]).
// ---------------------------------------------------------------------------
__global__ void k2_norm(float* __restrict__ lp, const float* __restrict__ ls)
{
    const int n4 = (BT_ROWS * VDIM) / 4;           // 16,777,216 float4
    int idx = blockIdx.x * blockDim.x + threadIdx.x;
    const int stride = gridDim.x * blockDim.x;
    float4* p = (float4*)lp;
    for (; idx < n4; idx += stride) {
        float l = ls[idx >> 9];                    // 512 float4 per row
        float4 v = p[idx];
        v.x -= l; v.y -= l; v.z -= l; v.w -= l;
        p[idx] = v;
    }
}

// ---------------------------------------------------------------------------
// K0: zero hist[2048] + accum[3] (contiguous in ws)
// ---------------------------------------------------------------------------
__global__ void k0_zero(float* __restrict__ ha)
{
    int i = blockIdx.x * blockDim.x + threadIdx.x;
    if (i < VDIM + 3) ha[i] = 0.f;
}

// ---------------------------------------------------------------------------
// K3: per-row small outputs. 1024 blocks x 256 thr, 32 rows/block.
//  - z_q_st[row] = e[amax[row]] * mask[row]   (z + sg(z_q - z) == z_q)
//  - commitment partial: sum (z - e[amax])^2 * mask
//  - smoothness partial: sum (z[t] - z[t-1])^2 * mask[t], t>0
//  - hist[amax] += mask (per row), masksum += mask (per block)
// ---------------------------------------------------------------------------
__global__ __launch_bounds__(256)
void k3_small(const float* __restrict__ z, const float* __restrict__ mask,
              const float* __restrict__ e, const int* __restrict__ amax,
              float* __restrict__ zq, float* __restrict__ hist,
              float* __restrict__ accum)
{
    const int tid = threadIdx.x;
    const int rbase = blockIdx.x * 32;
    float commit = 0.f, smooth = 0.f, mksum = 0.f;
    for (int rr = 0; rr < 32; ++rr) {
        const int row = rbase + rr;
        const int t = row & (TDIM - 1);
        const float mk = mask[row];
        const int a = amax[row];
        const float zv = z[(size_t)row * CDIM + tid];
        const float qa = e[(size_t)a * CDIM + tid];
        const float d = zv - qa;
        commit += d * d * mk;
        if (t > 0) {
            const float zp = z[(size_t)(row - 1) * CDIM + tid];
            const float dd = zv - zp;
            smooth += dd * dd * mk;
        }
        zq[(size_t)row * CDIM + tid] = qa * mk;
        if (tid == 0) { atomicAdd(&hist[a], mk); mksum += mk; }
    }
    #pragma unroll
    for (int off = 1; off < 64; off <<= 1) {
        commit += __shfl_xor(commit, off);
        smooth += __shfl_xor(smooth, off);
    }
    __shared__ float red[8];
    const int lane = tid & 63, wid = tid >> 6;
    if (lane == 0) { red[wid] = commit; red[4 + wid] = smooth; }
    __syncthreads();
    if (tid == 0) {
        atomicAdd(&accum[1], red[0] + red[1] + red[2] + red[3]);
        atomicAdd(&accum[2], red[4] + red[5] + red[6] + red[7]);
        atomicAdd(&accum[0], mksum);
    }
}

// ---------------------------------------------------------------------------
// K4: finalize scalars + e_mean.
// out tuple order: log_probs, z_q_st, smoothness, commitment, reinforce, e_mean
// reinforce = -mean(advantages) exactly (coef = exp(x - stop_grad(x)) == 1).
// ---------------------------------------------------------------------------
__global__ void k4_final(const float* __restrict__ adv, const float* __restrict__ hist,
                         const float* __restrict__ accum, float* __restrict__ sc,
                         float* __restrict__ emean)
{
    const float msum = accum[0];
    for (int v = threadIdx.x; v < VDIM; v += 256) emean[v] = hist[v] / msum;
    if (threadIdx.x == 0) {
        const float denom = msum * (float)CDIM;
        sc[0] = accum[2] / denom;   // smoothness_loss
        sc[1] = accum[1] / denom;   // commitment_loss
        float sa = 0.f;
        for (int k = 0; k < 32; ++k) sa += adv[k];   // B*BEAM = 32
        sc[2] = -sa / 32.f;         // reinforce_loss
    }
}

extern "C" void kernel_launch(void* const* d_in, const int* in_sizes, int n_in,
                              void* d_out, int out_size, void* d_ws, size_t ws_size,
                              hipStream_t stream)
{
    const float* z    = (const float*)d_in[0];
    const float* mask = (const float*)d_in[1];
    const float* e    = (const float*)d_in[2];
    const float* adv  = (const float*)d_in[3];

    float* lp    = (float*)d_out;                       // 67,108,864
    float* zq    = lp + (size_t)BT_ROWS * VDIM;         //  8,388,608
    float* sc    = zq + (size_t)BT_ROWS * CDIM;         //  3 scalars
    float* emean = sc + 3;                              //  2,048

    // workspace: ls[32768] f32 | amax[32768] i32 | hist[2048] | accum[3]
    float* ls    = (float*)d_ws;
    int*   amax  = (int*)((float*)d_ws + BT_ROWS);
    float* hist  = (float*)d_ws + 2 * BT_ROWS;
    float* accum = hist + VDIM;

    k0_zero   <<<9,    256, 0, stream>>>(hist);
    k1_gemm_lse<<<512, 256, 0, stream>>>(z, e, lp, ls, amax);
    k2_norm   <<<2048, 256, 0, stream>>>(lp, ls);
    k3_small  <<<1024, 256, 0, stream>>>(z, mask, e, amax, zq, hist, accum);
    k4_final  <<<1,    256, 0, stream>>>(adv, hist, accum, sc, emean);
}

// Round 5
// 636.803 us; speedup vs baseline: 1.8080x; 1.8080x over previous
//
#include <hip/hip_runtime.h>
#include <hip/hip_bf16.h>

#define BT_ROWS 32768   // B*T
#define CDIM    256
#define VDIM    2048
#define TDIM    2048
#define EHL_HALF (VDIM * CDIM)   // 524288 ushorts = 1MB per half

typedef __attribute__((ext_vector_type(4))) float f32x4;
typedef __attribute__((ext_vector_type(8))) short s16x8;

// bf16 round-to-nearest-even helpers (bit manipulation; no NaN in data)
__device__ __forceinline__ ushort bf16_rne(float v) {
    uint u = __float_as_uint(v);
    uint r = u + 0x7FFFu + ((u >> 16) & 1u);
    return (ushort)(r >> 16);
}
__device__ __forceinline__ float bf16_to_f(ushort h) {
    return __uint_as_float(((uint)h) << 16);
}

// ---------------------------------------------------------------------------
// Kp: convert E (f32 [2048][256]) into fragment-linear bf16 hi/lo halves.
// Target layout (per half): slot[cbg][ks][lane][j] (j=0..7 bf16) holds
//   E[col = cbg*16 + (lane&15)][k = ks*32 + (lane>>4)*8 + j]
// so K1's B-fragment load is one coalesced 16B load per lane.
// Stored into the zq region of d_out (2MB of 32MB); K3 overwrites zq later.
// ---------------------------------------------------------------------------
__global__ void kp_econv(const float* __restrict__ e, ushort* __restrict__ ehl)
{
    const int s   = blockIdx.x * 256 + threadIdx.x;   // 65536 slots
    const int col = s >> 5;
    const int kg  = s & 31;           // 8-k granule
    const int ks  = kg >> 2;
    const int lane = (kg & 3) * 16 + (col & 15);
    const int cbg = col >> 4;
    const float4 v0 = *(const float4*)&e[col * CDIM + kg * 8];
    const float4 v1 = *(const float4*)&e[col * CDIM + kg * 8 + 4];
    float vv[8] = {v0.x, v0.y, v0.z, v0.w, v1.x, v1.y, v1.z, v1.w};
    ushort h[8], l[8];
    #pragma unroll
    for (int j = 0; j < 8; ++j) {
        h[j] = bf16_rne(vv[j]);
        l[j] = bf16_rne(vv[j] - bf16_to_f(h[j]));
    }
    const int off = ((cbg * 8 + ks) * 64 + lane) * 8;
    uint4 hp, lp_;
    hp.x = h[0] | ((uint)h[1] << 16); hp.y = h[2] | ((uint)h[3] << 16);
    hp.z = h[4] | ((uint)h[5] << 16); hp.w = h[6] | ((uint)h[7] << 16);
    lp_.x = l[0] | ((uint)l[1] << 16); lp_.y = l[2] | ((uint)l[3] << 16);
    lp_.z = l[4] | ((uint)l[5] << 16); lp_.w = l[6] | ((uint)l[7] << 16);
    *(uint4*)&ehl[off] = hp;
    *(uint4*)&ehl[EHL_HALF + off] = lp_;
}

// ---------------------------------------------------------------------------
// K1: logits = Z @ E^T via bf16x3-split MFMA (Zh·Eh + Zh·El + Zl·Eh) + online
// row logsumexp + argmax. Block = 64 rows x V=2048; 4 waves x (64r x 128c);
// V chunks of 512. Z staged once to LDS as bf16 h/l fragment-linear
// [rb][ks][lane][8]: each wave stages one (rb,ks) subtile -> LDS writes are
// lane-contiguous 16B (conflict-free); ds_read_b128 at lane-stride 16B.
// B frags load coalesced from L2-hot fragment-linear ehl. 2 blocks/CU.
// MFMA 16x16x32 layouts: A lane: row=l&15, k=(l>>4)*8+j; B lane: col=l&15,
// k=(l>>4)*8+j; C/D: col=l&15, row=(l>>4)*4+reg (verified m89/m91).
// ---------------------------------------------------------------------------
__global__ __launch_bounds__(256, 2)
void k1_gemm_lse(const float* __restrict__ z, const ushort* __restrict__ ehl,
                 float* __restrict__ lp, float* __restrict__ ls_arr,
                 int* __restrict__ amax_arr)
{
    __shared__ __align__(16) ushort zsm[2 * 4 * 8 * 64 * 8];   // 64KB: [hl][rb][ks][lane][8]
    __shared__ float smx[256], ssm[256];
    __shared__ int   sam[256];

    const int tid  = threadIdx.x;
    const int w    = tid >> 6;       // wave 0..3
    const int l    = tid & 63;       // lane
    const int lg   = l >> 4;         // quarter-group (k-part / C row-part)
    const int li   = l & 15;         // within-group (col / A row)
    const int row0 = blockIdx.x * 64;

    // init stats
    smx[tid] = -3.0e38f; ssm[tid] = 0.f; sam[tid] = 0;

    // stage Z: 64 rows x 256 k -> bf16 h/l, fragment-linear.
    // s = p*256+tid -> rbks = s>>6 (one subtile per wave), lane = s&63.
    // row = (rbks>>3)*16 + (lane&15), kg = (rbks&7)*4 + (lane>>4).
    // Global: 16 rows x 128B contiguous per wave; LDS: lane-contiguous 16B.
    #pragma unroll
    for (int p = 0; p < 8; ++p) {
        const int s    = p * 256 + tid;
        const int rbks = s >> 6;
        const int lane = s & 63;
        const int row  = (rbks >> 3) * 16 + (lane & 15);
        const int kg   = (rbks & 7) * 4 + (lane >> 4);
        const float4 v0 = *(const float4*)&z[(size_t)(row0 + row) * CDIM + kg * 8];
        const float4 v1 = *(const float4*)&z[(size_t)(row0 + row) * CDIM + kg * 8 + 4];
        float vv[8] = {v0.x, v0.y, v0.z, v0.w, v1.x, v1.y, v1.z, v1.w};
        ushort h[8], lo[8];
        #pragma unroll
        for (int j = 0; j < 8; ++j) {
            h[j]  = bf16_rne(vv[j]);
            lo[j] = bf16_rne(vv[j] - bf16_to_f(h[j]));
        }
        const int off = (rbks * 64 + lane) * 8;
        uint4 hp, lq;
        hp.x = h[0] | ((uint)h[1] << 16); hp.y = h[2] | ((uint)h[3] << 16);
        hp.z = h[4] | ((uint)h[5] << 16); hp.w = h[6] | ((uint)h[7] << 16);
        lq.x = lo[0] | ((uint)lo[1] << 16); lq.y = lo[2] | ((uint)lo[3] << 16);
        lq.z = lo[4] | ((uint)lo[5] << 16); lq.w = lo[6] | ((uint)lo[7] << 16);
        *(uint4*)&zsm[off] = hp;
        *(uint4*)&zsm[16384 + off] = lq;
    }
    __syncthreads();

    const ushort* eh = ehl;
    const ushort* el = ehl + EHL_HALF;

    for (int chunk = 0; chunk < 4; ++chunk) {
        const int col0 = chunk * 512 + w * 128;
        const int cbg0 = col0 >> 4;
        f32x4 acc[4][8];
        #pragma unroll
        for (int rb = 0; rb < 4; ++rb)
            #pragma unroll
            for (int cb = 0; cb < 8; ++cb) acc[rb][cb] = (f32x4)0.f;

        #pragma unroll
        for (int ks = 0; ks < 8; ++ks) {
            s16x8 ah[4], al[4];
            #pragma unroll
            for (int rb = 0; rb < 4; ++rb) {
                ah[rb] = *(const s16x8*)&zsm[((rb * 8 + ks) * 64 + l) * 8];
                al[rb] = *(const s16x8*)&zsm[16384 + ((rb * 8 + ks) * 64 + l) * 8];
            }
            #pragma unroll
            for (int cb = 0; cb < 8; ++cb) {
                const s16x8 bh = *(const s16x8*)&eh[(((cbg0 + cb) * 8 + ks) * 64 + l) * 8];
                const s16x8 bl = *(const s16x8*)&el[(((cbg0 + cb) * 8 + ks) * 64 + l) * 8];
                #pragma unroll
                for (int rb = 0; rb < 4; ++rb) {
                    acc[rb][cb] = __builtin_amdgcn_mfma_f32_16x16x32_bf16(ah[rb], bh, acc[rb][cb], 0, 0, 0);
                    acc[rb][cb] = __builtin_amdgcn_mfma_f32_16x16x32_bf16(ah[rb], bl, acc[rb][cb], 0, 0, 0);
                    acc[rb][cb] = __builtin_amdgcn_mfma_f32_16x16x32_bf16(al[rb], bh, acc[rb][cb], 0, 0, 0);
                }
            }
        }

        // raw logit stores (normalized later by K2)
        #pragma unroll
        for (int rb = 0; rb < 4; ++rb)
            #pragma unroll
            for (int cb = 0; cb < 8; ++cb)
                #pragma unroll
                for (int r = 0; r < 4; ++r)
                    lp[(size_t)(row0 + rb * 16 + lg * 4 + r) * VDIM + col0 + cb * 16 + li] = acc[rb][cb][r];

        // per-chunk row stats: max/argmax/sumexp via 16-lane-group shuffles
        #pragma unroll
        for (int rb = 0; rb < 4; ++rb) {
            float rm[4]; int ri[4];
            #pragma unroll
            for (int r = 0; r < 4; ++r) { rm[r] = acc[rb][0][r]; ri[r] = col0 + li; }
            #pragma unroll
            for (int cb = 1; cb < 8; ++cb)
                #pragma unroll
                for (int r = 0; r < 4; ++r) {
                    const float v = acc[rb][cb][r];
                    if (v > rm[r]) { rm[r] = v; ri[r] = col0 + cb * 16 + li; }
                }
            #pragma unroll
            for (int mk = 1; mk < 16; mk <<= 1)
                #pragma unroll
                for (int r = 0; r < 4; ++r) {
                    const float ov = __shfl_xor(rm[r], mk);
                    const int   oi = __shfl_xor(ri[r], mk);
                    if (ov > rm[r] || (ov == rm[r] && oi < ri[r])) { rm[r] = ov; ri[r] = oi; }
                }
            float se[4] = {0.f, 0.f, 0.f, 0.f};
            #pragma unroll
            for (int cb = 0; cb < 8; ++cb)
                #pragma unroll
                for (int r = 0; r < 4; ++r) se[r] += __expf(acc[rb][cb][r] - rm[r]);
            #pragma unroll
            for (int mk = 1; mk < 16; mk <<= 1)
                #pragma unroll
                for (int r = 0; r < 4; ++r) se[r] += __shfl_xor(se[r], mk);
            if (li == 0) {
                #pragma unroll
                for (int r = 0; r < 4; ++r) {
                    const int sr = w * 64 + rb * 16 + lg * 4 + r;
                    const float mo = smx[sr], so = ssm[sr];
                    const float mn = fmaxf(mo, rm[r]);
                    ssm[sr] = so * __expf(mo - mn) + se[r] * __expf(rm[r] - mn);
                    smx[sr] = mn;
                    if (rm[r] > mo) sam[sr] = ri[r];
                }
            }
        }
    }

    __syncthreads();
    // cross-wave combine (waves hold disjoint col ranges of the same 64 rows)
    if (tid < 64) {
        const int row = tid;
        float m = smx[row]; int a = sam[row];
        #pragma unroll
        for (int ww = 1; ww < 4; ++ww) {
            const float mw = smx[ww * 64 + row];
            const int   aw = sam[ww * 64 + row];
            if (mw > m) { m = mw; a = aw; }
            else if (mw == m && aw < a) { a = aw; }
        }
        float s = 0.f;
        #pragma unroll
        for (int ww = 0; ww < 4; ++ww) s += ssm[ww * 64 + row] * expf(smx[ww * 64 + row] - m);
        ls_arr[row0 + row]   = m + logf(s);
        amax_arr[row0 + row] = a;
    }
}

// ---------------------------------------------------------------------------
// K2: in-place normalize raw logits -> log_probs (lp[row][v] -= ls[row]).
// ---------------------------------------------------------------------------
__global__ void k2_norm(float* __restrict__ lp, const float* __restrict__ ls)
{
    const int n4 = (BT_ROWS * VDIM) / 4;           // 16,777,216 float4
    int idx = blockIdx.x * blockDim.x + threadIdx.x;
    const int stride = gridDim.x * blockDim.x;
    float4* p = (float4*)lp;
    for (; idx < n4; idx += stride) {
        float lsv = ls[idx >> 9];                  // 512 float4 per row
        float4 v = p[idx];
        v.x -= lsv; v.y -= lsv; v.z -= lsv; v.w -= lsv;
        p[idx] = v;
    }
}

// ---------------------------------------------------------------------------
// K0: zero hist[2048] + accum[3] (contiguous in ws)
// ---------------------------------------------------------------------------
__global__ void k0_zero(float* __restrict__ ha)
{
    int i = blockIdx.x * blockDim.x + threadIdx.x;
    if (i < VDIM + 3) ha[i] = 0.f;
}

// ---------------------------------------------------------------------------
// K3: per-row small outputs. 1024 blocks x 256 thr, 32 rows/block.
//  - z_q_st[row] = e[amax[row]] * mask[row]   (z + sg(z_q - z) == z_q)
//  - commitment partial: sum (z - e[amax])^2 * mask
//  - smoothness partial: sum (z[t] - z[t-1])^2 * mask[t], t>0
//  - hist[amax] += mask (per row), masksum += mask (per block)
// ---------------------------------------------------------------------------
__global__ __launch_bounds__(256)
void k3_small(const float* __restrict__ z, const float* __restrict__ mask,
              const float* __restrict__ e, const int* __restrict__ amax,
              float* __restrict__ zq, float* __restrict__ hist,
              float* __restrict__ accum)
{
    const int tid = threadIdx.x;
    const int rbase = blockIdx.x * 32;
    float commit = 0.f, smooth = 0.f, mksum = 0.f;
    for (int rr = 0; rr < 32; ++rr) {
        const int row = rbase + rr;
        const int t = row & (TDIM - 1);
        const float mk = mask[row];
        const int a = amax[row];
        const float zv = z[(size_t)row * CDIM + tid];
        const float qa = e[(size_t)a * CDIM + tid];
        const float d = zv - qa;
        commit += d * d * mk;
        if (t > 0) {
            const float zp = z[(size_t)(row - 1) * CDIM + tid];
            const float dd = zv - zp;
            smooth += dd * dd * mk;
        }
        zq[(size_t)row * CDIM + tid] = qa * mk;
        if (tid == 0) { atomicAdd(&hist[a], mk); mksum += mk; }
    }
    #pragma unroll
    for (int off = 1; off < 64; off <<= 1) {
        commit += __shfl_xor(commit, off);
        smooth += __shfl_xor(smooth, off);
    }
    __shared__ float red[8];
    const int lane = tid & 63, wid = tid >> 6;
    if (lane == 0) { red[wid] = commit; red[4 + wid] = smooth; }
    __syncthreads();
    if (tid == 0) {
        atomicAdd(&accum[1], red[0] + red[1] + red[2] + red[3]);
        atomicAdd(&accum[2], red[4] + red[5] + red[6] + red[7]);
        atomicAdd(&accum[0], mksum);
    }
}

// ---------------------------------------------------------------------------
// K4: finalize scalars + e_mean.
// out tuple order: log_probs, z_q_st, smoothness, commitment, reinforce, e_mean
// reinforce = -mean(advantages) exactly (coef = exp(x - stop_grad(x)) == 1).
// ---------------------------------------------------------------------------
__global__ void k4_final(const float* __restrict__ adv, const float* __restrict__ hist,
                         const float* __restrict__ accum, float* __restrict__ sc,
                         float* __restrict__ emean)
{
    const float msum = accum[0];
    for (int v = threadIdx.x; v < VDIM; v += 256) emean[v] = hist[v] / msum;
    if (threadIdx.x == 0) {
        const float denom = msum * (float)CDIM;
        sc[0] = accum[2] / denom;   // smoothness_loss
        sc[1] = accum[1] / denom;   // commitment_loss
        float sa = 0.f;
        for (int k = 0; k < 32; ++k) sa += adv[k];   // B*BEAM = 32
        sc[2] = -sa / 32.f;         // reinforce_loss
    }
}

extern "C" void kernel_launch(void* const* d_in, const int* in_sizes, int n_in,
                              void* d_out, int out_size, void* d_ws, size_t ws_size,
                              hipStream_t stream)
{
    const float* z    = (const float*)d_in[0];
    const float* mask = (const float*)d_in[1];
    const float* e    = (const float*)d_in[2];
    const float* adv  = (const float*)d_in[3];

    float* lp    = (float*)d_out;                       // 67,108,864
    float* zq    = lp + (size_t)BT_ROWS * VDIM;         //  8,388,608
    float* sc    = zq + (size_t)BT_ROWS * CDIM;         //  3 scalars
    float* emean = sc + 3;                              //  2,048

    // ehl (bf16 hi/lo fragment-linear E, 2MB) borrows the zq region;
    // K1 consumes it before K3 overwrites zq. d_out re-poisoned each call ->
    // Kp rewrites it every call (same work every call).
    ushort* ehl = (ushort*)zq;

    // workspace: ls[32768] f32 | amax[32768] i32 | hist[2048] | accum[3]
    float* ls    = (float*)d_ws;
    int*   amax  = (int*)((float*)d_ws + BT_ROWS);
    float* hist  = (float*)d_ws + 2 * BT_ROWS;
    float* accum = hist + VDIM;

    k0_zero    <<<9,    256, 0, stream>>>(hist);
    kp_econv   <<<256,  256, 0, stream>>>(e, ehl);
    k1_gemm_lse<<<512,  256, 0, stream>>>(z, ehl, lp, ls, amax);
    k2_norm    <<<2048, 256, 0, stream>>>(lp, ls);
    k3_small   <<<1024, 256, 0, stream>>>(z, mask, e, amax, zq, hist, accum);
    k4_final   <<<1,    256, 0, stream>>>(adv, hist, accum, sc, emean);
}